// Round 3
// baseline (842.593 us; speedup 1.0000x reference)
//
#include <hip/hip_runtime.h>

#define SCAN_T 1024

// ---------------- CSR build ----------------

__global__ void k_hist(const int* __restrict__ row, int* __restrict__ cnt, int nnz) {
    int i = blockIdx.x * blockDim.x + threadIdx.x;
    if (i < nnz) atomicAdd(&cnt[row[i]], 1);
}

__global__ void k_blocksum(const int* __restrict__ cnt, int* __restrict__ bsum, int n) {
    __shared__ int sm[SCAN_T];
    int tid = threadIdx.x;
    int i = blockIdx.x * SCAN_T + tid;
    int x = (i < n) ? cnt[i] : 0;
    sm[tid] = x;
    __syncthreads();
    for (int off = SCAN_T / 2; off > 0; off >>= 1) {
        if (tid < off) sm[tid] += sm[tid + off];
        __syncthreads();
    }
    if (tid == 0) bsum[blockIdx.x] = sm[0];
}

// single block: in-place exclusive scan of bsum[nchunk]
__global__ void k_scan_bsum(int* __restrict__ bsum, int nchunk) {
    __shared__ int sm[SCAN_T];
    int tid = threadIdx.x;
    int running = 0;
    for (int base = 0; base < nchunk; base += SCAN_T) {
        int i = base + tid;
        int x = (i < nchunk) ? bsum[i] : 0;
        sm[tid] = x;
        __syncthreads();
        for (int off = 1; off < SCAN_T; off <<= 1) {
            int v = (tid >= off) ? sm[tid - off] : 0;
            __syncthreads();
            sm[tid] += v;
            __syncthreads();
        }
        int incl = sm[tid];
        int total = sm[SCAN_T - 1];
        if (i < nchunk) bsum[i] = running + incl - x;  // exclusive
        running += total;
        __syncthreads();
    }
}

__global__ void k_write_ptr(const int* __restrict__ cnt, const int* __restrict__ boff,
                            int* __restrict__ rp, int n) {
    __shared__ int sm[SCAN_T];
    int tid = threadIdx.x;
    int i = blockIdx.x * SCAN_T + tid;
    int x = (i < n) ? cnt[i] : 0;
    sm[tid] = x;
    __syncthreads();
    for (int off = 1; off < SCAN_T; off <<= 1) {
        int v = (tid >= off) ? sm[tid - off] : 0;
        __syncthreads();
        sm[tid] += v;
        __syncthreads();
    }
    int incl = sm[tid];
    int base = boff[blockIdx.x];
    if (i < n) rp[i] = base + incl - x;       // exclusive
    if (i == n - 1) rp[n] = base + incl;      // total
}

__global__ void k_scatter(const int* __restrict__ row, const int* __restrict__ col,
                          const float* __restrict__ val, int* __restrict__ fill,
                          int2* __restrict__ scv, int nnz) {
    int i = blockIdx.x * blockDim.x + threadIdx.x;
    if (i >= nnz) return;
    int r = row[i];
    int p = atomicAdd(&fill[r], 1);
    int2 v;
    v.x = col[i];
    v.y = __float_as_int(0.9f * val[i]);   // fold (1-alpha) here
    scv[p] = v;
}

// ---- SpMM: one wave per row; 16 edges/trip, 16 lanes/edge-group, float4/lane ----
// Tail: value-predicated only (no index clamp). Reads of scv up to 15 entries past
// a row's end are safe: mid-array they belong to the next row (valid col, val
// predicated to 0); the array carries 16 zeroed slack entries at the end.

__device__ __forceinline__ float4 shfl_xor4(float4 v, int m) {
    float4 r;
    r.x = __shfl_xor(v.x, m, 64);
    r.y = __shfl_xor(v.y, m, 64);
    r.z = __shfl_xor(v.z, m, 64);
    r.w = __shfl_xor(v.w, m, 64);
    return r;
}

__global__ __launch_bounds__(256) void k_spmm16(const float4* __restrict__ src,
                                                float4* __restrict__ dst,
                                                const float4* __restrict__ E,
                                                const int* __restrict__ rp,
                                                const int2* __restrict__ scv, int n) {
    int wid  = (blockIdx.x * blockDim.x + threadIdx.x) >> 6;  // row
    int lane = threadIdx.x & 63;
    if (wid >= n) return;
    int g = lane >> 4;   // edge group 0..3
    int q = lane & 15;   // feature quarter (4 floats each)
    int s = rp[wid];
    int e = rp[wid + 1];
    float4 acc = make_float4(0.f, 0.f, 0.f, 0.f);
    for (int j = s; j < e; j += 16) {
        int j0 = j + g, j1 = j + 4 + g, j2 = j + 8 + g, j3 = j + 12 + g;
        int2 c0 = scv[j0];
        int2 c1 = scv[j1];
        int2 c2 = scv[j2];
        int2 c3 = scv[j3];
        float v0 = (j0 < e) ? __int_as_float(c0.y) : 0.f;
        float v1 = (j1 < e) ? __int_as_float(c1.y) : 0.f;
        float v2 = (j2 < e) ? __int_as_float(c2.y) : 0.f;
        float v3 = (j3 < e) ? __int_as_float(c3.y) : 0.f;
        float4 a0 = src[c0.x * 16 + q];
        float4 a1 = src[c1.x * 16 + q];
        float4 a2 = src[c2.x * 16 + q];
        float4 a3 = src[c3.x * 16 + q];
        acc.x += v0 * a0.x; acc.y += v0 * a0.y; acc.z += v0 * a0.z; acc.w += v0 * a0.w;
        acc.x += v1 * a1.x; acc.y += v1 * a1.y; acc.z += v1 * a1.z; acc.w += v1 * a1.w;
        acc.x += v2 * a2.x; acc.y += v2 * a2.y; acc.z += v2 * a2.z; acc.w += v2 * a2.w;
        acc.x += v3 * a3.x; acc.y += v3 * a3.y; acc.z += v3 * a3.z; acc.w += v3 * a3.w;
    }
    // reduce the 4 edge-groups (lane bits 4 and 5)
    float4 t = shfl_xor4(acc, 16);
    acc.x += t.x; acc.y += t.y; acc.z += t.z; acc.w += t.w;
    t = shfl_xor4(acc, 32);
    acc.x += t.x; acc.y += t.y; acc.z += t.z; acc.w += t.w;
    if (g == 0) {  // lanes 0..15 write the row (256B coalesced)
        float4 ev = E[(size_t)wid * 16 + q];
        acc.x += 0.1f * ev.x; acc.y += 0.1f * ev.y;
        acc.z += 0.1f * ev.z; acc.w += 0.1f * ev.w;
        dst[(size_t)wid * 16 + q] = acc;
    }
}

// ---------------- launch ----------------

extern "C" void kernel_launch(void* const* d_in, const int* in_sizes, int n_in,
                              void* d_out, int out_size, void* d_ws, size_t ws_size,
                              hipStream_t stream) {
    const float* E    = (const float*)d_in[0];
    const float* eval = (const float*)d_in[1];
    const int*   erow = (const int*)d_in[2];
    const int*   ecol = (const int*)d_in[3];
    const int D   = 64;
    const int N   = in_sizes[0] / D;
    const int NNZ = in_sizes[1];
    float* out = (float*)d_out;

    char* w = (char*)d_ws;
    size_t o = 0;
    auto alloc = [&](size_t bytes) -> char* {
        char* p = w + o;
        o = (o + bytes + 255) & ~(size_t)255;
        return p;
    };
    int*   cnt  = (int*)alloc((size_t)N * 4);
    int*   rp   = (int*)alloc((size_t)(N + 1) * 4);
    int*   fill = (int*)alloc((size_t)N * 4);
    int nchunk  = (N + SCAN_T - 1) / SCAN_T;
    int*   bsum = (int*)alloc((size_t)nchunk * 4);
    int2*  scv  = (int2*)alloc(((size_t)NNZ + 16) * 8);  // +16 zeroed slack entries
    float* pbuf = (float*)alloc((size_t)N * D * 4);

    hipMemsetAsync(cnt, 0, (size_t)N * 4, stream);
    hipMemsetAsync(scv + NNZ, 0, 16 * 8, stream);  // slack for past-end trip reads
    k_hist<<<(NNZ + 255) / 256, 256, 0, stream>>>(erow, cnt, NNZ);
    k_blocksum<<<nchunk, SCAN_T, 0, stream>>>(cnt, bsum, N);
    k_scan_bsum<<<1, SCAN_T, 0, stream>>>(bsum, nchunk);
    k_write_ptr<<<nchunk, SCAN_T, 0, stream>>>(cnt, bsum, rp, N);
    hipMemcpyAsync(fill, rp, (size_t)N * 4, hipMemcpyDeviceToDevice, stream);
    k_scatter<<<(NNZ + 255) / 256, 256, 0, stream>>>(erow, ecol, eval, fill, scv, NNZ);

    const int waves_per_block = 4;  // 256 threads
    int nblk = (N + waves_per_block - 1) / waves_per_block;
    const float* src = E;
    for (int it = 0; it < 10; ++it) {
        float* dst = (it & 1) ? out : pbuf;  // it 9 (10th) -> out
        k_spmm16<<<nblk, 256, 0, stream>>>((const float4*)src, (float4*)dst, (const float4*)E,
                                           rp, scv, N);
        src = dst;
    }
}

// Round 4
// 793.369 us; speedup vs baseline: 1.0620x; 1.0620x over previous
//
#include <hip/hip_runtime.h>

#define SCAN_T 1024

// ---------------- CSR build ----------------

__global__ void k_hist(const int* __restrict__ row, int* __restrict__ cnt, int nnz) {
    int i = blockIdx.x * blockDim.x + threadIdx.x;
    if (i < nnz) atomicAdd(&cnt[row[i]], 1);
}

__global__ void k_blocksum(const int* __restrict__ cnt, int* __restrict__ bsum, int n) {
    __shared__ int sm[SCAN_T];
    int tid = threadIdx.x;
    int i = blockIdx.x * SCAN_T + tid;
    int x = (i < n) ? cnt[i] : 0;
    sm[tid] = x;
    __syncthreads();
    for (int off = SCAN_T / 2; off > 0; off >>= 1) {
        if (tid < off) sm[tid] += sm[tid + off];
        __syncthreads();
    }
    if (tid == 0) bsum[blockIdx.x] = sm[0];
}

// single block: in-place exclusive scan of bsum[nchunk]
__global__ void k_scan_bsum(int* __restrict__ bsum, int nchunk) {
    __shared__ int sm[SCAN_T];
    int tid = threadIdx.x;
    int running = 0;
    for (int base = 0; base < nchunk; base += SCAN_T) {
        int i = base + tid;
        int x = (i < nchunk) ? bsum[i] : 0;
        sm[tid] = x;
        __syncthreads();
        for (int off = 1; off < SCAN_T; off <<= 1) {
            int v = (tid >= off) ? sm[tid - off] : 0;
            __syncthreads();
            sm[tid] += v;
            __syncthreads();
        }
        int incl = sm[tid];
        int total = sm[SCAN_T - 1];
        if (i < nchunk) bsum[i] = running + incl - x;  // exclusive
        running += total;
        __syncthreads();
    }
}

__global__ void k_write_ptr(const int* __restrict__ cnt, const int* __restrict__ boff,
                            int* __restrict__ rp, int n) {
    __shared__ int sm[SCAN_T];
    int tid = threadIdx.x;
    int i = blockIdx.x * SCAN_T + tid;
    int x = (i < n) ? cnt[i] : 0;
    sm[tid] = x;
    __syncthreads();
    for (int off = 1; off < SCAN_T; off <<= 1) {
        int v = (tid >= off) ? sm[tid - off] : 0;
        __syncthreads();
        sm[tid] += v;
        __syncthreads();
    }
    int incl = sm[tid];
    int base = boff[blockIdx.x];
    if (i < n) rp[i] = base + incl - x;       // exclusive
    if (i == n - 1) rp[n] = base + incl;      // total
}

__global__ void k_scatter(const int* __restrict__ row, const int* __restrict__ col,
                          const float* __restrict__ val, int* __restrict__ fill,
                          int2* __restrict__ scv, int nnz) {
    int i = blockIdx.x * blockDim.x + threadIdx.x;
    if (i >= nnz) return;
    int r = row[i];
    int p = atomicAdd(&fill[r], 1);
    int2 v;
    v.x = col[i];
    v.y = __float_as_int(0.9f * val[i]);   // fold (1-alpha) here
    scv[p] = v;
}

// ---- SpMM: one wave per row; 16 edges/trip (4 gathers in flight), 16 lanes/edge,
// float4/lane. Tail: index CLAMPED to e-1 (duplicate same-address loads merge in
// the coalescer -> no extra cache traffic) + value predication for correctness.

__device__ __forceinline__ float4 shfl_xor4(float4 v, int m) {
    float4 r;
    r.x = __shfl_xor(v.x, m, 64);
    r.y = __shfl_xor(v.y, m, 64);
    r.z = __shfl_xor(v.z, m, 64);
    r.w = __shfl_xor(v.w, m, 64);
    return r;
}

__global__ __launch_bounds__(256) void k_spmm16c(const float4* __restrict__ src,
                                                 float4* __restrict__ dst,
                                                 const float4* __restrict__ E,
                                                 const int* __restrict__ rp,
                                                 const int2* __restrict__ scv, int n) {
    int wid  = (blockIdx.x * blockDim.x + threadIdx.x) >> 6;  // row
    int lane = threadIdx.x & 63;
    if (wid >= n) return;
    int g = lane >> 4;   // edge group 0..3
    int q = lane & 15;   // feature quarter (4 floats each)
    int s = rp[wid];
    int e = rp[wid + 1];
    float4 acc = make_float4(0.f, 0.f, 0.f, 0.f);
    for (int j = s; j < e; j += 16) {
        int j0 = j + g, j1 = j + 4 + g, j2 = j + 8 + g, j3 = j + 12 + g;
        int i0 = min(j0, e - 1);
        int i1 = min(j1, e - 1);
        int i2 = min(j2, e - 1);
        int i3 = min(j3, e - 1);
        int2 c0 = scv[i0];
        int2 c1 = scv[i1];
        int2 c2 = scv[i2];
        int2 c3 = scv[i3];
        float v0 = (j0 < e) ? __int_as_float(c0.y) : 0.f;
        float v1 = (j1 < e) ? __int_as_float(c1.y) : 0.f;
        float v2 = (j2 < e) ? __int_as_float(c2.y) : 0.f;
        float v3 = (j3 < e) ? __int_as_float(c3.y) : 0.f;
        float4 a0 = src[c0.x * 16 + q];
        float4 a1 = src[c1.x * 16 + q];
        float4 a2 = src[c2.x * 16 + q];
        float4 a3 = src[c3.x * 16 + q];
        acc.x += v0 * a0.x; acc.y += v0 * a0.y; acc.z += v0 * a0.z; acc.w += v0 * a0.w;
        acc.x += v1 * a1.x; acc.y += v1 * a1.y; acc.z += v1 * a1.z; acc.w += v1 * a1.w;
        acc.x += v2 * a2.x; acc.y += v2 * a2.y; acc.z += v2 * a2.z; acc.w += v2 * a2.w;
        acc.x += v3 * a3.x; acc.y += v3 * a3.y; acc.z += v3 * a3.z; acc.w += v3 * a3.w;
    }
    // reduce the 4 edge-groups (lane bits 4 and 5)
    float4 t = shfl_xor4(acc, 16);
    acc.x += t.x; acc.y += t.y; acc.z += t.z; acc.w += t.w;
    t = shfl_xor4(acc, 32);
    acc.x += t.x; acc.y += t.y; acc.z += t.z; acc.w += t.w;
    if (g == 0) {  // lanes 0..15 write the row (256B coalesced)
        float4 ev = E[(size_t)wid * 16 + q];
        acc.x += 0.1f * ev.x; acc.y += 0.1f * ev.y;
        acc.z += 0.1f * ev.z; acc.w += 0.1f * ev.w;
        dst[(size_t)wid * 16 + q] = acc;
    }
}

// ---------------- launch ----------------

extern "C" void kernel_launch(void* const* d_in, const int* in_sizes, int n_in,
                              void* d_out, int out_size, void* d_ws, size_t ws_size,
                              hipStream_t stream) {
    const float* E    = (const float*)d_in[0];
    const float* eval = (const float*)d_in[1];
    const int*   erow = (const int*)d_in[2];
    const int*   ecol = (const int*)d_in[3];
    const int D   = 64;
    const int N   = in_sizes[0] / D;
    const int NNZ = in_sizes[1];
    float* out = (float*)d_out;

    char* w = (char*)d_ws;
    size_t o = 0;
    auto alloc = [&](size_t bytes) -> char* {
        char* p = w + o;
        o = (o + bytes + 255) & ~(size_t)255;
        return p;
    };
    int*   cnt  = (int*)alloc((size_t)N * 4);
    int*   rp   = (int*)alloc((size_t)(N + 1) * 4);
    int*   fill = (int*)alloc((size_t)N * 4);
    int nchunk  = (N + SCAN_T - 1) / SCAN_T;
    int*   bsum = (int*)alloc((size_t)nchunk * 4);
    int2*  scv  = (int2*)alloc((size_t)NNZ * 8);
    float* pbuf = (float*)alloc((size_t)N * D * 4);

    hipMemsetAsync(cnt, 0, (size_t)N * 4, stream);
    k_hist<<<(NNZ + 255) / 256, 256, 0, stream>>>(erow, cnt, NNZ);
    k_blocksum<<<nchunk, SCAN_T, 0, stream>>>(cnt, bsum, N);
    k_scan_bsum<<<1, SCAN_T, 0, stream>>>(bsum, nchunk);
    k_write_ptr<<<nchunk, SCAN_T, 0, stream>>>(cnt, bsum, rp, N);
    hipMemcpyAsync(fill, rp, (size_t)N * 4, hipMemcpyDeviceToDevice, stream);
    k_scatter<<<(NNZ + 255) / 256, 256, 0, stream>>>(erow, ecol, eval, fill, scv, NNZ);

    const int waves_per_block = 4;  // 256 threads
    int nblk = (N + waves_per_block - 1) / waves_per_block;
    const float* src = E;
    for (int it = 0; it < 10; ++it) {
        float* dst = (it & 1) ? out : pbuf;  // it 9 (10th) -> out
        k_spmm16c<<<nblk, 256, 0, stream>>>((const float4*)src, (float4*)dst, (const float4*)E,
                                            rp, scv, N);
        src = dst;
    }
}